// Round 2
// baseline (545.456 us; speedup 1.0000x reference)
//
#include <hip/hip_runtime.h>
#include <hip/hip_bf16.h>

#define BB 32
#define NN 1024
#define MM 1024
#define DD 128

typedef __bf16 bf16;
typedef bf16 bf16x8 __attribute__((ext_vector_type(8)));
typedef bf16 bf16x4 __attribute__((ext_vector_type(4)));
typedef float f32x4 __attribute__((ext_vector_type(4)));

#define LOG2E 1.4426950408889634f
#define LN2   0.6931471805599453f
#define ESHIFT 30.5f
#define ESHIFT_C 5.6757e-14f   // exp(-30.5)

__device__ __forceinline__ bf16x8 ld8(const bf16* p) {
    return *reinterpret_cast<const bf16x8*>(p);
}

__device__ __forceinline__ bf16x8 cvt8(const float* p) {
    float4 a = reinterpret_cast<const float4*>(p)[0];
    float4 c = reinterpret_cast<const float4*>(p)[1];
    bf16x8 r;
    r[0]=(bf16)a.x; r[1]=(bf16)a.y; r[2]=(bf16)a.z; r[3]=(bf16)a.w;
    r[4]=(bf16)c.x; r[5]=(bf16)c.y; r[6]=(bf16)c.z; r[7]=(bf16)c.w;
    return r;
}

// ---------- prep: fp32 -> bf16 straight convert ----------
__global__ void k_convert(const float* __restrict__ src, bf16* __restrict__ dst) {
    int i = blockIdx.x * 256 + threadIdx.x;
    float4 v = reinterpret_cast<const float4*>(src)[i];
    bf16x4 o; o[0]=(bf16)v.x; o[1]=(bf16)v.y; o[2]=(bf16)v.z; o[3]=(bf16)v.w;
    reinterpret_cast<bf16x4*>(dst)[i] = o;
}

// ---------- prep: [B][R][C] fp32 -> [B][C][R] bf16 ----------
__global__ void k_transpose(const float* __restrict__ src, bf16* __restrict__ dst,
                            int R, int C) {
    __shared__ float tile[32][33];
    int b = blockIdx.z;
    int c0 = blockIdx.x * 32, r0 = blockIdx.y * 32;
    const float* s = src + (size_t)b * R * C;
    bf16* d = dst + (size_t)b * R * C;
    int tx = threadIdx.x, ty = threadIdx.y;
#pragma unroll
    for (int j = 0; j < 4; ++j)
        tile[ty + j*8][tx] = s[(size_t)(r0 + ty + j*8) * C + c0 + tx];
    __syncthreads();
#pragma unroll
    for (int j = 0; j < 4; ++j)
        d[(size_t)(c0 + ty + j*8) * R + r0 + tx] = (bf16)tile[tx][ty + j*8];
}

// ---------- coeff: Xc = Xs * tanh(W @ A_w^T + A_b), bf16 out ----------
__global__ __launch_bounds__(256) void k_coeff(
    const float* __restrict__ Xs, const float* __restrict__ W,
    const float* __restrict__ Aw, const float* __restrict__ Ab,
    bf16* __restrict__ Xc) {
    int ntile = blockIdx.x, b = blockIdx.y;
    int tid = threadIdx.x;
    int w = tid >> 6, lane = tid & 63, quad = lane >> 4, l16 = lane & 15;
    int nbase = ntile * 64 + w * 16;

    f32x4 accZ[8];
#pragma unroll
    for (int ef = 0; ef < 8; ++ef) accZ[ef] = {0.f, 0.f, 0.f, 0.f};

    const float* Wb = W + ((size_t)b * NN + nbase + l16) * DD;
#pragma unroll
    for (int ks = 0; ks < 4; ++ks) {
        bf16x8 aW = cvt8(Wb + ks * 32 + quad * 8);
#pragma unroll
        for (int ef = 0; ef < 8; ++ef) {
            bf16x8 bA = cvt8(Aw + (size_t)(ef * 16 + l16) * DD + ks * 32 + quad * 8);
            accZ[ef] = __builtin_amdgcn_mfma_f32_16x16x32_bf16(aW, bA, accZ[ef], 0, 0, 0);
        }
    }
#pragma unroll
    for (int ef = 0; ef < 8; ++ef) {
        float ab = Ab[ef * 16 + l16];
#pragma unroll
        for (int r = 0; r < 4; ++r) {
            float z = accZ[ef][r] + ab;
            z = fminf(fmaxf(z, -12.f), 12.f);
            float t = __builtin_amdgcn_exp2f(z * (2.f * LOG2E));
            float c = (t - 1.f) / (t + 1.f);
            int n = nbase + quad * 4 + r;
            size_t idx = ((size_t)b * NN + n) * DD + ef * 16 + l16;
            Xc[idx] = (bf16)(Xs[idx] * c);
        }
    }
}

// ---------- merged main: role 0 = attention_x + s, role 1 = attention_y ----------
// Grid (32, BB): blockIdx.x < 16 -> x-role (ntile), >= 16 -> y-role (mtile).
// 4 waves/block, each wave owns 16 output rows and iterates all 16 opposing
// tiles. NO atomics anywhere: softmax-x denom = in-register rowsum (x-role);
// softmax-y denom = in-register rowsum of the y-role's own E values.
__global__ __launch_bounds__(256, 4) void k_main(
    const bf16* __restrict__ Xc, const bf16* __restrict__ Ysb,
    const bf16* __restrict__ YsT, const bf16* __restrict__ XsT,
    float* __restrict__ out_x, float* __restrict__ out_y,
    float* __restrict__ out_s) {
    __shared__ __align__(16) bf16 Et[4][16][72];     // 9 KB, wave-private
    __shared__ __align__(16) float Sst[4][16][68];   // 17 KB, wave-private (x-role)

    int bx = blockIdx.x, b = blockIdx.y;
    int role = bx >> 4, tile = bx & 15;
    int tid = threadIdx.x;
    int w = tid >> 6, lane = tid & 63, quad = lane >> 4, l16 = lane & 15;
    int rbase = tile * 64 + w * 16;   // this wave's 16 output rows

    if (role == 0) {
        // ===== attention_x + s =====
        const bf16* XcRow = Xc + ((size_t)b * NN + rbase + l16) * DD;
        bf16x8 aX[4];
#pragma unroll
        for (int ks = 0; ks < 4; ++ks) aX[ks] = ld8(XcRow + ks * 32 + quad * 8);

        f32x4 accU[8];
#pragma unroll
        for (int df = 0; df < 8; ++df) accU[df] = {0.f, 0.f, 0.f, 0.f};
        float rowsum[4] = {0.f, 0.f, 0.f, 0.f};

        const bf16* Ysb_b = Ysb + (size_t)b * MM * DD;
        const bf16* YsT_b = YsT + (size_t)b * DD * MM;
        float* s_b = out_s + (size_t)b * NN * MM;

#pragma unroll 2
        for (int mt = 0; mt < 16; ++mt) {
            bf16x8 bYv[16];
#pragma unroll
            for (int ks = 0; ks < 4; ++ks)
#pragma unroll
                for (int mf = 0; mf < 4; ++mf)
                    bYv[ks*4+mf] = ld8(Ysb_b + (size_t)(mt * 64 + mf * 16 + l16) * DD + ks * 32 + quad * 8);

            f32x4 accS[4];
#pragma unroll
            for (int mf = 0; mf < 4; ++mf) accS[mf] = {0.f, 0.f, 0.f, 0.f};
#pragma unroll
            for (int ks = 0; ks < 4; ++ks)
#pragma unroll
                for (int mf = 0; mf < 4; ++mf)
                    accS[mf] = __builtin_amdgcn_mfma_f32_16x16x32_bf16(aX[ks], bYv[ks*4+mf], accS[mf], 0, 0, 0);

            // issue GEMM2 B-fragments now; latency hides under epilogue VALU
            bf16x8 bTv[16];
#pragma unroll
            for (int k2 = 0; k2 < 2; ++k2)
#pragma unroll
                for (int df = 0; df < 8; ++df)
                    bTv[k2*8+df] = ld8(YsT_b + (size_t)(df * 16 + l16) * MM + mt * 64 + k2 * 32 + quad * 8);

            // epilogue: softplus -> LDS stage, E -> Et, rowsum in registers
#pragma unroll
            for (int mf = 0; mf < 4; ++mf) {
#pragma unroll
                for (int r = 0; r < 4; ++r) {
                    float x = accS[mf][r];
                    float ax = fabsf(x);
                    float sp = fmaxf(x, 0.f) +
                               LN2 * __builtin_amdgcn_logf(1.f + __builtin_amdgcn_exp2f(-ax * LOG2E));
                    Sst[w][quad * 4 + r][mf * 16 + l16] = sp - 0.5f;
                    float E = __builtin_amdgcn_exp2f((x - ESHIFT) * LOG2E) + ESHIFT_C;
                    bf16 Eb = (bf16)E;
                    rowsum[r] += (float)Eb;
                    Et[w][quad * 4 + r][mf * 16 + l16] = Eb;
                }
            }
            // dump staged s tile as full-line float4 stores (4 instrs/wave)
#pragma unroll
            for (int i = 0; i < 4; ++i) {
                int row = i * 4 + (lane >> 4);
                int col = (lane & 15) * 4;
                float4 v = *reinterpret_cast<const float4*>(&Sst[w][row][col]);
                *reinterpret_cast<float4*>(s_b + (size_t)(rbase + row) * MM + mt * 64 + col) = v;
            }
            // GEMM2: U += E @ Ys_tile (wave-private Et, no barrier needed)
#pragma unroll
            for (int k2 = 0; k2 < 2; ++k2) {
                bf16x8 aE = *reinterpret_cast<const bf16x8*>(&Et[w][l16][k2 * 32 + quad * 8]);
#pragma unroll
                for (int df = 0; df < 8; ++df)
                    accU[df] = __builtin_amdgcn_mfma_f32_16x16x32_bf16(aE, bTv[k2*8+df], accU[df], 0, 0, 0);
            }
        }

        float inv[4];
#pragma unroll
        for (int r = 0; r < 4; ++r) {
            float rs = rowsum[r];
            rs += __shfl_xor(rs, 1); rs += __shfl_xor(rs, 2);
            rs += __shfl_xor(rs, 4); rs += __shfl_xor(rs, 8);
            inv[r] = 1.f / rs;
        }
#pragma unroll
        for (int df = 0; df < 8; ++df)
#pragma unroll
            for (int r = 0; r < 4; ++r)
                out_x[((size_t)b * NN + rbase + quad * 4 + r) * DD + df * 16 + l16] = accU[df][r] * inv[r];
    } else {
        // ===== attention_y (self-computed denominator) =====
        const bf16* YRow = Ysb + ((size_t)b * MM + rbase + l16) * DD;
        bf16x8 aY[4];
#pragma unroll
        for (int ks = 0; ks < 4; ++ks) aY[ks] = ld8(YRow + ks * 32 + quad * 8);

        f32x4 accV[8];
#pragma unroll
        for (int df = 0; df < 8; ++df) accV[df] = {0.f, 0.f, 0.f, 0.f};
        float rowsum[4] = {0.f, 0.f, 0.f, 0.f};

        const bf16* Xc_b = Xc + (size_t)b * NN * DD;
        const bf16* XsT_b = XsT + (size_t)b * DD * NN;

#pragma unroll 2
        for (int nt = 0; nt < 16; ++nt) {
            bf16x8 bXv[16];
#pragma unroll
            for (int ks = 0; ks < 4; ++ks)
#pragma unroll
                for (int nf = 0; nf < 4; ++nf)
                    bXv[ks*4+nf] = ld8(Xc_b + (size_t)(nt * 64 + nf * 16 + l16) * DD + ks * 32 + quad * 8);

            f32x4 accS[4];
#pragma unroll
            for (int nf = 0; nf < 4; ++nf) accS[nf] = {0.f, 0.f, 0.f, 0.f};
#pragma unroll
            for (int ks = 0; ks < 4; ++ks)
#pragma unroll
                for (int nf = 0; nf < 4; ++nf)
                    accS[nf] = __builtin_amdgcn_mfma_f32_16x16x32_bf16(aY[ks], bXv[ks*4+nf], accS[nf], 0, 0, 0);

            bf16x8 bTv[16];
#pragma unroll
            for (int k2 = 0; k2 < 2; ++k2)
#pragma unroll
                for (int df = 0; df < 8; ++df)
                    bTv[k2*8+df] = ld8(XsT_b + (size_t)(df * 16 + l16) * NN + nt * 64 + k2 * 32 + quad * 8);

#pragma unroll
            for (int nf = 0; nf < 4; ++nf) {
#pragma unroll
                for (int r = 0; r < 4; ++r) {
                    float x = accS[nf][r];   // s^T[m][n] == s[n][m]
                    float E = __builtin_amdgcn_exp2f((x - ESHIFT) * LOG2E) + ESHIFT_C;
                    bf16 Eb = (bf16)E;
                    rowsum[r] += (float)Eb;   // softmax-y denominator for row m
                    Et[w][quad * 4 + r][nf * 16 + l16] = Eb;
                }
            }
#pragma unroll
            for (int k2 = 0; k2 < 2; ++k2) {
                bf16x8 aE = *reinterpret_cast<const bf16x8*>(&Et[w][l16][k2 * 32 + quad * 8]);
#pragma unroll
                for (int df = 0; df < 8; ++df)
                    accV[df] = __builtin_amdgcn_mfma_f32_16x16x32_bf16(aE, bTv[k2*8+df], accV[df], 0, 0, 0);
            }
        }

        float inv[4];
#pragma unroll
        for (int r = 0; r < 4; ++r) {
            float rs = rowsum[r];
            rs += __shfl_xor(rs, 1); rs += __shfl_xor(rs, 2);
            rs += __shfl_xor(rs, 4); rs += __shfl_xor(rs, 8);
            inv[r] = 1.f / rs;
        }
#pragma unroll
        for (int df = 0; df < 8; ++df)
#pragma unroll
            for (int r = 0; r < 4; ++r)
                out_y[((size_t)b * MM + rbase + quad * 4 + r) * DD + df * 16 + l16] = accV[df][r] * inv[r];
    }
}

extern "C" void kernel_launch(void* const* d_in, const int* in_sizes, int n_in,
                              void* d_out, int out_size, void* d_ws, size_t ws_size,
                              hipStream_t stream) {
    const float* Xs = (const float*)d_in[0];
    const float* Ys = (const float*)d_in[1];
    const float* W  = (const float*)d_in[2];
    const float* Aw = (const float*)d_in[3];
    const float* Ab = (const float*)d_in[4];

    char* ws = (char*)d_ws;
    bf16*  Xc     = (bf16*)(ws);                 //  8 MB
    bf16*  Ysb    = (bf16*)(ws + 8388608);       //  8 MB
    bf16*  YsT    = (bf16*)(ws + 16777216);      //  8 MB
    bf16*  XsT    = (bf16*)(ws + 25165824);      //  8 MB

    float* out_x = (float*)d_out;
    float* out_y = out_x + (size_t)BB * NN * DD;
    float* out_s = out_y + (size_t)BB * MM * DD;

    k_convert<<<dim3(BB * MM * DD / 4 / 256), 256, 0, stream>>>(Ys, Ysb);
    k_transpose<<<dim3(DD / 32, MM / 32, BB), dim3(32, 8), 0, stream>>>(Ys, YsT, MM, DD);
    k_transpose<<<dim3(DD / 32, NN / 32, BB), dim3(32, 8), 0, stream>>>(Xs, XsT, NN, DD);
    k_coeff<<<dim3(NN / 64, BB), 256, 0, stream>>>(Xs, W, Aw, Ab, Xc);
    k_main<<<dim3(32, BB), 256, 0, stream>>>(Xc, Ysb, YsT, XsT, out_x, out_y, out_s);
}

// Round 3
// 467.895 us; speedup vs baseline: 1.1658x; 1.1658x over previous
//
#include <hip/hip_runtime.h>
#include <hip/hip_bf16.h>

#define BB 32
#define NN 1024
#define MM 1024
#define DD 128

typedef __bf16 bf16;
typedef bf16 bf16x8 __attribute__((ext_vector_type(8)));
typedef float f32x4 __attribute__((ext_vector_type(4)));

#define LOG2E 1.4426950408889634f
#define LN2   0.6931471805599453f
#define ESHIFT 30.5f
#define ESHIFT_C 5.6757e-14f   // exp(-30.5)

__device__ __forceinline__ bf16x8 ld8(const bf16* p) {
    return *reinterpret_cast<const bf16x8*>(p);
}

__device__ __forceinline__ bf16x8 cvt8(const float* p) {
    float4 a = reinterpret_cast<const float4*>(p)[0];
    float4 c = reinterpret_cast<const float4*>(p)[1];
    bf16x8 r;
    r[0]=(bf16)a.x; r[1]=(bf16)a.y; r[2]=(bf16)a.z; r[3]=(bf16)a.w;
    r[4]=(bf16)c.x; r[5]=(bf16)c.y; r[6]=(bf16)c.z; r[7]=(bf16)c.w;
    return r;
}

// ---------- prep: one kernel does Ys->bf16, Ys->T, Xs->T ----------
// grid (4, 64, BB): y<32 -> Ys tile (write Ysb + YsT), y>=32 -> Xs tile (XsT).
__global__ void k_prep(const float* __restrict__ Xs, const float* __restrict__ Ys,
                       bf16* __restrict__ Ysb, bf16* __restrict__ YsT,
                       bf16* __restrict__ XsT) {
    __shared__ float tile[32][33];
    int b = blockIdx.z;
    int yy = blockIdx.y;
    int isY = (yy < 32);
    int r0 = (yy & 31) * 32, c0 = blockIdx.x * 32;
    const float* s = (isY ? Ys : Xs) + (size_t)b * 1024 * DD;
    int tx = threadIdx.x, ty = threadIdx.y;
    float v[4];
#pragma unroll
    for (int j = 0; j < 4; ++j) {
        v[j] = s[(size_t)(r0 + ty + j*8) * DD + c0 + tx];
        tile[ty + j*8][tx] = v[j];
    }
    if (isY) {
        bf16* d = Ysb + (size_t)b * MM * DD;
#pragma unroll
        for (int j = 0; j < 4; ++j)
            d[(size_t)(r0 + ty + j*8) * DD + c0 + tx] = (bf16)v[j];
    }
    __syncthreads();
    bf16* dT = (isY ? YsT : XsT) + (size_t)b * DD * 1024;
#pragma unroll
    for (int j = 0; j < 4; ++j)
        dT[(size_t)(c0 + ty + j*8) * 1024 + r0 + tx] = (bf16)tile[tx][ty + j*8];
}

// ---------- coeff: Xc = Xs * tanh(W @ A_w^T + A_b), bf16 out ----------
__global__ __launch_bounds__(256) void k_coeff(
    const float* __restrict__ Xs, const float* __restrict__ W,
    const float* __restrict__ Aw, const float* __restrict__ Ab,
    bf16* __restrict__ Xc) {
    int ntile = blockIdx.x, b = blockIdx.y;
    int tid = threadIdx.x;
    int w = tid >> 6, lane = tid & 63, quad = lane >> 4, l16 = lane & 15;
    int nbase = ntile * 64 + w * 16;

    f32x4 accZ[8];
#pragma unroll
    for (int ef = 0; ef < 8; ++ef) accZ[ef] = {0.f, 0.f, 0.f, 0.f};

    const float* Wb = W + ((size_t)b * NN + nbase + l16) * DD;
#pragma unroll
    for (int ks = 0; ks < 4; ++ks) {
        bf16x8 aW = cvt8(Wb + ks * 32 + quad * 8);
#pragma unroll
        for (int ef = 0; ef < 8; ++ef) {
            bf16x8 bA = cvt8(Aw + (size_t)(ef * 16 + l16) * DD + ks * 32 + quad * 8);
            accZ[ef] = __builtin_amdgcn_mfma_f32_16x16x32_bf16(aW, bA, accZ[ef], 0, 0, 0);
        }
    }
#pragma unroll
    for (int ef = 0; ef < 8; ++ef) {
        float ab = Ab[ef * 16 + l16];
#pragma unroll
        for (int r = 0; r < 4; ++r) {
            float z = accZ[ef][r] + ab;
            z = fminf(fmaxf(z, -12.f), 12.f);
            float t = __builtin_amdgcn_exp2f(z * (2.f * LOG2E));
            float c = (t - 1.f) / (t + 1.f);
            int n = nbase + quad * 4 + r;
            size_t idx = ((size_t)b * NN + n) * DD + ef * 16 + l16;
            Xc[idx] = (bf16)(Xs[idx] * c);
        }
    }
}

// ---------- merged main: role 0 = attention_x + s, role 1 = attention_y ----------
// Block swizzle homes each batch on ONE XCD so its ~1 MB working set lives in
// that XCD's 4 MB L2 (4 batches/XCD). No atomics anywhere; each wave owns 16
// output rows, iterates all 16 opposing tiles, denominators in registers.
__global__ __launch_bounds__(256, 3) void k_main(
    const bf16* __restrict__ Xc, const bf16* __restrict__ Ysb,
    const bf16* __restrict__ YsT, const bf16* __restrict__ XsT,
    float* __restrict__ out_x, float* __restrict__ out_y,
    float* __restrict__ out_s) {
    __shared__ __align__(16) bf16 Et[4][16][72];   // 9 KB, wave-private

    int L = blockIdx.x + 32 * blockIdx.y;          // 0..1023
    int xcd = L & 7, sidx = L >> 3;
    int b = xcd + 8 * (sidx & 3);                  // batch -> fixed XCD
    int t = sidx >> 2;                             // 0..31
    int role = t >> 4, tile = t & 15;
    int tid = threadIdx.x;
    int w = tid >> 6, lane = tid & 63, quad = lane >> 4, l16 = lane & 15;
    int rbase = tile * 64 + w * 16;                // this wave's 16 output rows

    if (role == 0) {
        // ===== attention_x + s =====
        const bf16* XcRow = Xc + ((size_t)b * NN + rbase + l16) * DD;
        bf16x8 aX[4];
#pragma unroll
        for (int ks = 0; ks < 4; ++ks) aX[ks] = ld8(XcRow + ks * 32 + quad * 8);

        f32x4 accU[8];
#pragma unroll
        for (int df = 0; df < 8; ++df) accU[df] = {0.f, 0.f, 0.f, 0.f};
        float rowsum[4] = {0.f, 0.f, 0.f, 0.f};

        const bf16* Ysb_b = Ysb + (size_t)b * MM * DD;
        const bf16* YsT_b = YsT + (size_t)b * DD * MM;
        float* s_b = out_s + (size_t)b * NN * MM;

#pragma unroll 1
        for (int mt = 0; mt < 16; ++mt) {
            f32x4 accS[4];
#pragma unroll
            for (int mf = 0; mf < 4; ++mf) accS[mf] = {0.f, 0.f, 0.f, 0.f};
#pragma unroll
            for (int ks = 0; ks < 4; ++ks) {
                bf16x8 bY[4];
#pragma unroll
                for (int mf = 0; mf < 4; ++mf)
                    bY[mf] = ld8(Ysb_b + (size_t)(mt * 64 + mf * 16 + l16) * DD + ks * 32 + quad * 8);
#pragma unroll
                for (int mf = 0; mf < 4; ++mf)
                    accS[mf] = __builtin_amdgcn_mfma_f32_16x16x32_bf16(aX[ks], bY[mf], accS[mf], 0, 0, 0);
            }
            // prefetch GEMM2 k2=0 slice; latency hides under epilogue VALU
            bf16x8 bT0[8];
#pragma unroll
            for (int df = 0; df < 8; ++df)
                bT0[df] = ld8(YsT_b + (size_t)(df * 16 + l16) * MM + mt * 64 + quad * 8);

            // epilogue: softplus -> s (direct), E -> Et, rowsum in registers
#pragma unroll
            for (int mf = 0; mf < 4; ++mf) {
#pragma unroll
                for (int r = 0; r < 4; ++r) {
                    float x = accS[mf][r];
                    float ax = fabsf(x);
                    float sp = fmaxf(x, 0.f) +
                               LN2 * __builtin_amdgcn_logf(1.f + __builtin_amdgcn_exp2f(-ax * LOG2E));
                    int n = rbase + quad * 4 + r;
                    s_b[(size_t)n * MM + mt * 64 + mf * 16 + l16] = sp - 0.5f;
                    float E = __builtin_amdgcn_exp2f((x - ESHIFT) * LOG2E) + ESHIFT_C;
                    bf16 Eb = (bf16)E;
                    rowsum[r] += (float)Eb;
                    Et[w][quad * 4 + r][mf * 16 + l16] = Eb;
                }
            }
            // GEMM2: U += E @ Ys_tile (wave-private Et, no barrier needed)
            bf16x8 bT1[8];
#pragma unroll
            for (int df = 0; df < 8; ++df)
                bT1[df] = ld8(YsT_b + (size_t)(df * 16 + l16) * MM + mt * 64 + 32 + quad * 8);
            bf16x8 aE0 = *reinterpret_cast<const bf16x8*>(&Et[w][l16][quad * 8]);
#pragma unroll
            for (int df = 0; df < 8; ++df)
                accU[df] = __builtin_amdgcn_mfma_f32_16x16x32_bf16(aE0, bT0[df], accU[df], 0, 0, 0);
            bf16x8 aE1 = *reinterpret_cast<const bf16x8*>(&Et[w][l16][32 + quad * 8]);
#pragma unroll
            for (int df = 0; df < 8; ++df)
                accU[df] = __builtin_amdgcn_mfma_f32_16x16x32_bf16(aE1, bT1[df], accU[df], 0, 0, 0);
        }

        float inv[4];
#pragma unroll
        for (int r = 0; r < 4; ++r) {
            float rs = rowsum[r];
            rs += __shfl_xor(rs, 1); rs += __shfl_xor(rs, 2);
            rs += __shfl_xor(rs, 4); rs += __shfl_xor(rs, 8);
            inv[r] = 1.f / rs;
        }
#pragma unroll
        for (int df = 0; df < 8; ++df)
#pragma unroll
            for (int r = 0; r < 4; ++r)
                out_x[((size_t)b * NN + rbase + quad * 4 + r) * DD + df * 16 + l16] = accU[df][r] * inv[r];
    } else {
        // ===== attention_y (self-computed denominator, no colsum) =====
        const bf16* YRow = Ysb + ((size_t)b * MM + rbase + l16) * DD;
        bf16x8 aY[4];
#pragma unroll
        for (int ks = 0; ks < 4; ++ks) aY[ks] = ld8(YRow + ks * 32 + quad * 8);

        f32x4 accV[8];
#pragma unroll
        for (int df = 0; df < 8; ++df) accV[df] = {0.f, 0.f, 0.f, 0.f};
        float rowsum[4] = {0.f, 0.f, 0.f, 0.f};

        const bf16* Xc_b = Xc + (size_t)b * NN * DD;
        const bf16* XsT_b = XsT + (size_t)b * DD * NN;

#pragma unroll 1
        for (int nt = 0; nt < 16; ++nt) {
            f32x4 accS[4];
#pragma unroll
            for (int nf = 0; nf < 4; ++nf) accS[nf] = {0.f, 0.f, 0.f, 0.f};
#pragma unroll
            for (int ks = 0; ks < 4; ++ks) {
                bf16x8 bX[4];
#pragma unroll
                for (int nf = 0; nf < 4; ++nf)
                    bX[nf] = ld8(Xc_b + (size_t)(nt * 64 + nf * 16 + l16) * DD + ks * 32 + quad * 8);
#pragma unroll
                for (int nf = 0; nf < 4; ++nf)
                    accS[nf] = __builtin_amdgcn_mfma_f32_16x16x32_bf16(aY[ks], bX[nf], accS[nf], 0, 0, 0);
            }
            bf16x8 bT0[8];
#pragma unroll
            for (int df = 0; df < 8; ++df)
                bT0[df] = ld8(XsT_b + (size_t)(df * 16 + l16) * NN + nt * 64 + quad * 8);

#pragma unroll
            for (int nf = 0; nf < 4; ++nf) {
#pragma unroll
                for (int r = 0; r < 4; ++r) {
                    float x = accS[nf][r];   // s^T[m][n] == s[n][m]
                    float E = __builtin_amdgcn_exp2f((x - ESHIFT) * LOG2E) + ESHIFT_C;
                    bf16 Eb = (bf16)E;
                    rowsum[r] += (float)Eb;  // softmax-y denominator for row m
                    Et[w][quad * 4 + r][nf * 16 + l16] = Eb;
                }
            }
            bf16x8 bT1[8];
#pragma unroll
            for (int df = 0; df < 8; ++df)
                bT1[df] = ld8(XsT_b + (size_t)(df * 16 + l16) * NN + nt * 64 + 32 + quad * 8);
            bf16x8 aE0 = *reinterpret_cast<const bf16x8*>(&Et[w][l16][quad * 8]);
#pragma unroll
            for (int df = 0; df < 8; ++df)
                accV[df] = __builtin_amdgcn_mfma_f32_16x16x32_bf16(aE0, bT0[df], accV[df], 0, 0, 0);
            bf16x8 aE1 = *reinterpret_cast<const bf16x8*>(&Et[w][l16][32 + quad * 8]);
#pragma unroll
            for (int df = 0; df < 8; ++df)
                accV[df] = __builtin_amdgcn_mfma_f32_16x16x32_bf16(aE1, bT1[df], accV[df], 0, 0, 0);
        }

        float inv[4];
#pragma unroll
        for (int r = 0; r < 4; ++r) {
            float rs = rowsum[r];
            rs += __shfl_xor(rs, 1); rs += __shfl_xor(rs, 2);
            rs += __shfl_xor(rs, 4); rs += __shfl_xor(rs, 8);
            inv[r] = 1.f / rs;
        }
#pragma unroll
        for (int df = 0; df < 8; ++df)
#pragma unroll
            for (int r = 0; r < 4; ++r)
                out_y[((size_t)b * MM + rbase + quad * 4 + r) * DD + df * 16 + l16] = accV[df][r] * inv[r];
    }
}

extern "C" void kernel_launch(void* const* d_in, const int* in_sizes, int n_in,
                              void* d_out, int out_size, void* d_ws, size_t ws_size,
                              hipStream_t stream) {
    const float* Xs = (const float*)d_in[0];
    const float* Ys = (const float*)d_in[1];
    const float* W  = (const float*)d_in[2];
    const float* Aw = (const float*)d_in[3];
    const float* Ab = (const float*)d_in[4];

    char* ws = (char*)d_ws;
    bf16*  Xc     = (bf16*)(ws);                 //  8 MB
    bf16*  Ysb    = (bf16*)(ws + 8388608);       //  8 MB
    bf16*  YsT    = (bf16*)(ws + 16777216);      //  8 MB
    bf16*  XsT    = (bf16*)(ws + 25165824);      //  8 MB

    float* out_x = (float*)d_out;
    float* out_y = out_x + (size_t)BB * NN * DD;
    float* out_s = out_y + (size_t)BB * MM * DD;

    k_prep<<<dim3(DD / 32, 64, BB), dim3(32, 8), 0, stream>>>(Xs, Ys, Ysb, YsT, XsT);
    k_coeff<<<dim3(NN / 64, BB), 256, 0, stream>>>(Xs, W, Aw, Ab, Xc);
    k_main<<<dim3(32, BB), 256, 0, stream>>>(Xc, Ysb, YsT, XsT, out_x, out_y, out_s);
}

// Round 4
// 294.259 us; speedup vs baseline: 1.8537x; 1.5901x over previous
//
#include <hip/hip_runtime.h>
#include <hip/hip_bf16.h>

#define BB 32
#define NN 1024
#define MM 1024
#define DD 128

typedef __bf16 bf16;
typedef bf16 bf16x8 __attribute__((ext_vector_type(8)));
typedef bf16 bf16x4 __attribute__((ext_vector_type(4)));
typedef float f32x4 __attribute__((ext_vector_type(4)));

#define LOG2E 1.4426950408889634f
#define LN2   0.6931471805599453f
#define ESHIFT 30.5f
#define ESHIFT_C 5.6757e-14f   // exp(-30.5)

__device__ __forceinline__ bf16x8 ld8(const bf16* p) {
    return *reinterpret_cast<const bf16x8*>(p);
}

__device__ __forceinline__ bf16x8 cvt8(const float* p) {
    float4 a = reinterpret_cast<const float4*>(p)[0];
    float4 c = reinterpret_cast<const float4*>(p)[1];
    bf16x8 r;
    r[0]=(bf16)a.x; r[1]=(bf16)a.y; r[2]=(bf16)a.z; r[3]=(bf16)a.w;
    r[4]=(bf16)c.x; r[5]=(bf16)c.y; r[6]=(bf16)c.z; r[7]=(bf16)c.w;
    return r;
}

// ---------- prep: Ys->bf16 + Ys->T + Xs->T, vectorized both directions ----------
// grid (64, BB): x<32 -> Ys row-tile (write Ysb + YsT), x>=32 -> Xs row-tile (XsT).
// Block 256: phase 1 reads 32x128 f32 tile via float4 (16B/lane), phase 2 writes
// the transpose with 32 B contiguous per thread.
__global__ void k_prep(const float* __restrict__ Xs, const float* __restrict__ Ys,
                       bf16* __restrict__ Ysb, bf16* __restrict__ YsT,
                       bf16* __restrict__ XsT) {
    __shared__ float tile[32][129];
    int b = blockIdx.y;
    int yy = blockIdx.x;
    int isY = (yy < 32);
    int r0 = (yy & 31) * 32;
    const float* s = (isY ? Ys : Xs) + (size_t)b * 1024 * DD;
    int tid = threadIdx.x;
    int c4 = (tid & 31) * 4;
#pragma unroll
    for (int p = 0; p < 4; ++p) {
        int r = p * 8 + (tid >> 5);
        float4 v = *reinterpret_cast<const float4*>(s + (size_t)(r0 + r) * DD + c4);
        tile[r][c4] = v.x; tile[r][c4 + 1] = v.y; tile[r][c4 + 2] = v.z; tile[r][c4 + 3] = v.w;
        if (isY) {
            bf16x4 o; o[0] = (bf16)v.x; o[1] = (bf16)v.y; o[2] = (bf16)v.z; o[3] = (bf16)v.w;
            *reinterpret_cast<bf16x4*>(Ysb + (size_t)b * MM * DD + (size_t)(r0 + r) * DD + c4) = o;
        }
    }
    __syncthreads();
    bf16* dT = (isY ? YsT : XsT) + (size_t)b * DD * 1024;
    int c = tid >> 1, rh = (tid & 1) * 16;
    bf16x8 o0, o1;
#pragma unroll
    for (int j = 0; j < 8; ++j) o0[j] = (bf16)tile[rh + j][c];
#pragma unroll
    for (int j = 0; j < 8; ++j) o1[j] = (bf16)tile[rh + 8 + j][c];
    *reinterpret_cast<bf16x8*>(dT + (size_t)c * 1024 + r0 + rh) = o0;
    *reinterpret_cast<bf16x8*>(dT + (size_t)c * 1024 + r0 + rh + 8) = o1;
}

// ---------- coeff: Xc = Xs * tanh(W @ A_w^T + A_b), bf16 out ----------
__global__ __launch_bounds__(256) void k_coeff(
    const float* __restrict__ Xs, const float* __restrict__ W,
    const float* __restrict__ Aw, const float* __restrict__ Ab,
    bf16* __restrict__ Xc) {
    int ntile = blockIdx.x, b = blockIdx.y;
    int tid = threadIdx.x;
    int w = tid >> 6, lane = tid & 63, quad = lane >> 4, l16 = lane & 15;
    int nbase = ntile * 64 + w * 16;

    f32x4 accZ[8];
#pragma unroll
    for (int ef = 0; ef < 8; ++ef) accZ[ef] = {0.f, 0.f, 0.f, 0.f};

    const float* Wb = W + ((size_t)b * NN + nbase + l16) * DD;
#pragma unroll
    for (int ks = 0; ks < 4; ++ks) {
        bf16x8 aW = cvt8(Wb + ks * 32 + quad * 8);
#pragma unroll
        for (int ef = 0; ef < 8; ++ef) {
            bf16x8 bA = cvt8(Aw + (size_t)(ef * 16 + l16) * DD + ks * 32 + quad * 8);
            accZ[ef] = __builtin_amdgcn_mfma_f32_16x16x32_bf16(aW, bA, accZ[ef], 0, 0, 0);
        }
    }
#pragma unroll
    for (int ef = 0; ef < 8; ++ef) {
        float ab = Ab[ef * 16 + l16];
#pragma unroll
        for (int r = 0; r < 4; ++r) {
            float z = accZ[ef][r] + ab;
            z = fminf(fmaxf(z, -12.f), 12.f);
            float t = __builtin_amdgcn_exp2f(z * (2.f * LOG2E));
            float c = (t - 1.f) / (t + 1.f);
            int n = nbase + quad * 4 + r;
            size_t idx = ((size_t)b * NN + n) * DD + ef * 16 + l16;
            Xc[idx] = (bf16)(Xs[idx] * c);
        }
    }
}

// ---------- merged main with LDS double-buffered tile staging ----------
// role 0: attention_x + s (A-rows = Xc, B = Ys/YsT); role 1: attention_y
// (A-rows = Ysb, B = Xc/XsT). Per iteration the BLOCK stages the 64-row B-tile
// (16 KB) + its transpose slice (16 KB) into LDS once (reg-staged, issue at
// iteration top / ds_write at bottom = T14), XOR-swizzled against the 16-way
// bank conflict of 256B/128B row strides. One barrier per iteration.
__global__ __launch_bounds__(256, 2) void k_main(
    const bf16* __restrict__ Xc, const bf16* __restrict__ Ysb,
    const bf16* __restrict__ YsT, const bf16* __restrict__ XsT,
    float* __restrict__ out_x, float* __restrict__ out_y,
    float* __restrict__ out_s) {
    __shared__ __align__(16) bf16 stage[2][16384];   // 2 x 32 KB: [0:16K)=B-tile, [16K:32K)=BT-tile
    __shared__ __align__(16) bf16 Et[4][16][72];     // 9 KB, wave-private

    int L = blockIdx.x + 32 * blockIdx.y;            // 0..1023
    int xcd = L & 7, sidx = L >> 3;
    int b = xcd + 8 * (sidx & 3);                    // batch -> fixed XCD (L2 homing)
    int t = sidx >> 2;
    int role = t >> 4, tile = t & 15;
    int tid = threadIdx.x;
    int w = tid >> 6, lane = tid & 63, quad = lane >> 4, l16 = lane & 15;
    int rbase = tile * 64 + w * 16;

    const bf16* Arow  = (role == 0 ? Xc : Ysb) + ((size_t)b * 1024 + rbase + l16) * DD;
    const bf16* Bmat  = (role == 0 ? Ysb : Xc) + (size_t)b * 1024 * DD;
    const bf16* BTmat = (role == 0 ? YsT : XsT) + (size_t)b * DD * 1024;
    float* s_b = out_s + (size_t)b * NN * MM;
    float* outp = (role == 0 ? out_x : out_y);

    // persistent A fragments
    bf16x8 aX[4];
#pragma unroll
    for (int ks = 0; ks < 4; ++ks) aX[ks] = ld8(Arow + ks * 32 + quad * 8);

    // ---- staging geometry: wave w owns linear bytes [w*8K, (w+1)*8K) of the 32 KB region
    int isA = (w < 2);                                // waves 0,1: B-tile; 2,3: BT-tile
    uint32_t wroff[8];                                // swizzled LDS byte offsets
    uint32_t soff[8];                                 // source byte offsets (tile-relative)
#pragma unroll
    for (int i = 0; i < 8; ++i) {
        uint32_t o = (uint32_t)(w * 8 + i) * 1024 + (uint32_t)lane * 16;
        if (isA) {                                    // rows of 256 B
            wroff[i] = o ^ (((o >> 8) & 7) << 4);
            soff[i]  = o;                             // contiguous 16 KB in global
        } else {                                      // rows of 128 B, global row stride 2048 B
            uint32_t j = o - 16384;
            wroff[i] = 16384 + (j ^ (((j >> 7) & 7) << 4));
            soff[i]  = (j >> 7) * 2048 + (j & 127);
        }
    }
    const char* srcbase = (const char*)(isA ? Bmat : BTmat);
    uint32_t tstride = isA ? 16384u : 128u;

    // ---- prologue: stage tile 0
    bf16x8 stg[8];
#pragma unroll
    for (int i = 0; i < 8; ++i)
        stg[i] = *reinterpret_cast<const bf16x8*>(srcbase + soff[i]);
#pragma unroll
    for (int i = 0; i < 8; ++i)
        *reinterpret_cast<bf16x8*>((char*)&stage[0][0] + wroff[i]) = stg[i];
    __syncthreads();

    f32x4 accU[8];
#pragma unroll
    for (int df = 0; df < 8; ++df) accU[df] = {0.f, 0.f, 0.f, 0.f};
    float rowsum[4] = {0.f, 0.f, 0.f, 0.f};
    uint32_t xq = (uint32_t)(l16 & 7) << 4;           // read-side swizzle term
    int cur = 0;

#pragma unroll 1
    for (int tt = 0; tt < 16; ++tt) {
        // 1. issue next-tile global loads (latency spans the whole compute phase)
        if (tt < 15) {
#pragma unroll
            for (int i = 0; i < 8; ++i)
                stg[i] = *reinterpret_cast<const bf16x8*>(srcbase + (size_t)(tt + 1) * tstride + soff[i]);
        }
        __builtin_amdgcn_sched_barrier(0);            // pin load issue above compute

        const char* sb = (const char*)&stage[cur][0];
        // 2. GEMM1: S = A @ Btile^T from LDS
        f32x4 accS[4];
#pragma unroll
        for (int mf = 0; mf < 4; ++mf) accS[mf] = {0.f, 0.f, 0.f, 0.f};
#pragma unroll
        for (int ks = 0; ks < 4; ++ks) {
            bf16x8 bY[4];
#pragma unroll
            for (int mf = 0; mf < 4; ++mf)
                bY[mf] = *reinterpret_cast<const bf16x8*>(
                    sb + (uint32_t)(mf * 16 + l16) * 256 + (((uint32_t)(ks * 64 + quad * 16)) ^ xq));
#pragma unroll
            for (int mf = 0; mf < 4; ++mf)
                accS[mf] = __builtin_amdgcn_mfma_f32_16x16x32_bf16(aX[ks], bY[mf], accS[mf], 0, 0, 0);
        }
        // 3. epilogue: E (always), softplus + s store (role 0 only)
#pragma unroll
        for (int mf = 0; mf < 4; ++mf) {
#pragma unroll
            for (int r = 0; r < 4; ++r) {
                float x = accS[mf][r];
                float E = __builtin_amdgcn_exp2f((x - ESHIFT) * LOG2E) + ESHIFT_C;
                bf16 Eb = (bf16)E;
                rowsum[r] += (float)Eb;
                Et[w][quad * 4 + r][mf * 16 + l16] = Eb;
            }
            if (role == 0) {
#pragma unroll
                for (int r = 0; r < 4; ++r) {
                    float x = accS[mf][r];
                    float ax = fabsf(x);
                    float sp = fmaxf(x, 0.f) +
                               LN2 * __builtin_amdgcn_logf(1.f + __builtin_amdgcn_exp2f(-ax * LOG2E));
                    s_b[(size_t)(rbase + quad * 4 + r) * MM + tt * 64 + mf * 16 + l16] = sp - 0.5f;
                }
            }
        }
        // 4. GEMM2: U += E @ Btile (BT slice from LDS)
#pragma unroll
        for (int half = 0; half < 2; ++half) {
            bf16x8 aE = *reinterpret_cast<const bf16x8*>(&Et[w][l16][half * 32 + quad * 8]);
            bf16x8 bT[8];
#pragma unroll
            for (int df = 0; df < 8; ++df)
                bT[df] = *reinterpret_cast<const bf16x8*>(
                    sb + 16384 + (uint32_t)(df * 16 + l16) * 128 + (((uint32_t)(half * 64 + quad * 16)) ^ xq));
#pragma unroll
            for (int df = 0; df < 8; ++df)
                accU[df] = __builtin_amdgcn_mfma_f32_16x16x32_bf16(aE, bT[df], accU[df], 0, 0, 0);
        }
        __builtin_amdgcn_sched_barrier(0);            // pin ds_write below compute
        // 5. write staged tile into the other buffer, then one barrier
        if (tt < 15) {
#pragma unroll
            for (int i = 0; i < 8; ++i)
                *reinterpret_cast<bf16x8*>((char*)&stage[cur ^ 1][0] + wroff[i]) = stg[i];
        }
        __syncthreads();
        cur ^= 1;
    }

    // denominators + output
    float inv[4];
#pragma unroll
    for (int r = 0; r < 4; ++r) {
        float rs = rowsum[r];
        rs += __shfl_xor(rs, 1); rs += __shfl_xor(rs, 2);
        rs += __shfl_xor(rs, 4); rs += __shfl_xor(rs, 8);
        inv[r] = 1.f / rs;
    }
#pragma unroll
    for (int df = 0; df < 8; ++df)
#pragma unroll
        for (int r = 0; r < 4; ++r)
            outp[((size_t)b * 1024 + rbase + quad * 4 + r) * DD + df * 16 + l16] = accU[df][r] * inv[r];
}

extern "C" void kernel_launch(void* const* d_in, const int* in_sizes, int n_in,
                              void* d_out, int out_size, void* d_ws, size_t ws_size,
                              hipStream_t stream) {
    const float* Xs = (const float*)d_in[0];
    const float* Ys = (const float*)d_in[1];
    const float* W  = (const float*)d_in[2];
    const float* Aw = (const float*)d_in[3];
    const float* Ab = (const float*)d_in[4];

    char* ws = (char*)d_ws;
    bf16*  Xc     = (bf16*)(ws);                 //  8 MB
    bf16*  Ysb    = (bf16*)(ws + 8388608);       //  8 MB
    bf16*  YsT    = (bf16*)(ws + 16777216);      //  8 MB
    bf16*  XsT    = (bf16*)(ws + 25165824);      //  8 MB

    float* out_x = (float*)d_out;
    float* out_y = out_x + (size_t)BB * NN * DD;
    float* out_s = out_y + (size_t)BB * MM * DD;

    k_prep<<<dim3(64, BB), 256, 0, stream>>>(Xs, Ys, Ysb, YsT, XsT);
    k_coeff<<<dim3(NN / 64, BB), 256, 0, stream>>>(Xs, W, Aw, Ab, Xc);
    k_main<<<dim3(32, BB), 256, 0, stream>>>(Xc, Ysb, YsT, XsT, out_x, out_y, out_s);
}